// Round 6
// baseline (114.125 us; speedup 1.0000x reference)
//
#include <hip/hip_runtime.h>

typedef unsigned short u16;
typedef __attribute__((ext_vector_type(8))) short short8;
typedef __attribute__((ext_vector_type(8))) __bf16 bf16x8;
typedef __attribute__((ext_vector_type(4))) float f32x4;
typedef __attribute__((ext_vector_type(4))) unsigned int u32x4;

#define MFMA_BF16(a, b, c) __builtin_amdgcn_mfma_f32_16x16x32_bf16((a), (b), (c), 0, 0, 0)

__device__ __forceinline__ u16 f2bf(float f) {
    unsigned u = __builtin_bit_cast(unsigned, f);
    u += 0x7FFFu + ((u >> 16) & 1u);   // round-to-nearest-even; inputs finite
    return (u16)(u >> 16);
}

// v_cvt_pk_bf16_f32: dst = {bf16(lo), bf16(hi)} packed, RNE
__device__ __forceinline__ unsigned cvt_pk_bf16(float lo, float hi) {
    unsigned r;
    asm("v_cvt_pk_bf16_f32 %0, %1, %2" : "=v"(r) : "v"(lo), "v"(hi));
    return r;
}

// raw v_exp_f32 (exp2); denormal range flushes to 0, which is what we want
__device__ __forceinline__ float fast_exp2(float x) {
    float r;
    asm("v_exp_f32 %0, %1" : "=v"(r) : "v"(x));
    return r;
}

// ---------------------------------------------------------------------------
// Projection GEMM: O[n][c] = bf16( (X[n][:] . W[c][:] + b[c]) * alpha )
// alpha_q = SCALE * log2(e) so attention softmax can use exp2 directly.
// ---------------------------------------------------------------------------
__global__ __launch_bounds__(256) void proj_gemm(
    const float* __restrict__ Xq, const float* __restrict__ Xk, const float* __restrict__ Xv,
    const float* __restrict__ Wq, const float* __restrict__ Wk, const float* __restrict__ Wv,
    const float* __restrict__ bq, const float* __restrict__ bk, const float* __restrict__ bv,
    u16* __restrict__ Oq, u16* __restrict__ Ok, u16* __restrict__ Ov)
{
    constexpr int K = 512, N = 512;
    const int z = blockIdx.z;
    const float* __restrict__ X = (z == 0) ? Xq : (z == 1) ? Xk : Xv;
    const float* __restrict__ W = (z == 0) ? Wq : (z == 1) ? Wk : Wv;
    const float* __restrict__ bias = (z == 0) ? bq : (z == 1) ? bk : bv;
    u16* __restrict__ O = (z == 0) ? Oq : (z == 1) ? Ok : Ov;
    const float alpha = (z == 0) ? 0.125f * 1.44269504088896f : 1.0f;

    __shared__ u16 lA[128 * 64];
    __shared__ u16 lB[128 * 64];

    const int tid = threadIdx.x, lane = tid & 63, w = tid >> 6;
    const int wr = w >> 1, wc = w & 1;
    const int bm = blockIdx.x, bn = blockIdx.y;
    const int r0 = tid >> 3, cc = tid & 7;

    f32x4 acc[4][4];
    for (int m = 0; m < 4; ++m)
        for (int n = 0; n < 4; ++n)
            acc[m][n] = f32x4{0.f, 0.f, 0.f, 0.f};

    for (int kt = 0; kt < K; kt += 64) {
        __syncthreads();
        for (int p = 0; p < 4; ++p) {
            int r = r0 + p * 32;
            {
                const float4* g = (const float4*)(X + (size_t)(bm * 128 + r) * K + kt + cc * 8);
                float4 f0 = g[0], f1 = g[1];
                short8 v;
                v[0] = (short)f2bf(f0.x); v[1] = (short)f2bf(f0.y);
                v[2] = (short)f2bf(f0.z); v[3] = (short)f2bf(f0.w);
                v[4] = (short)f2bf(f1.x); v[5] = (short)f2bf(f1.y);
                v[6] = (short)f2bf(f1.z); v[7] = (short)f2bf(f1.w);
                *(short8*)&lA[r * 64 + ((cc ^ (r & 7)) << 3)] = v;
            }
            {
                const float4* g = (const float4*)(W + (size_t)(bn * 128 + r) * K + kt + cc * 8);
                float4 f0 = g[0], f1 = g[1];
                short8 v;
                v[0] = (short)f2bf(f0.x); v[1] = (short)f2bf(f0.y);
                v[2] = (short)f2bf(f0.z); v[3] = (short)f2bf(f0.w);
                v[4] = (short)f2bf(f1.x); v[5] = (short)f2bf(f1.y);
                v[6] = (short)f2bf(f1.z); v[7] = (short)f2bf(f1.w);
                *(short8*)&lB[r * 64 + ((cc ^ (r & 7)) << 3)] = v;
            }
        }
        __syncthreads();
        for (int kk = 0; kk < 2; ++kk) {
            bf16x8 af[4], bfr[4];
            for (int m = 0; m < 4; ++m) {
                int row = wr * 64 + m * 16 + (lane & 15);
                af[m] = *(const bf16x8*)&lA[row * 64 + (((kk * 4 + (lane >> 4)) ^ (row & 7)) << 3)];
            }
            for (int n = 0; n < 4; ++n) {
                int row = wc * 64 + n * 16 + (lane & 15);
                bfr[n] = *(const bf16x8*)&lB[row * 64 + (((kk * 4 + (lane >> 4)) ^ (row & 7)) << 3)];
            }
            for (int m = 0; m < 4; ++m)
                for (int n = 0; n < 4; ++n)
                    acc[m][n] = MFMA_BF16(af[m], bfr[n], acc[m][n]);
        }
    }
    for (int m = 0; m < 4; ++m)
        for (int n = 0; n < 4; ++n) {
            int row = bm * 128 + wr * 64 + m * 16 + ((lane >> 4) << 2);
            int col = bn * 128 + wc * 64 + n * 16 + (lane & 15);
            float bv_ = bias[col];
            for (int i = 0; i < 4; ++i) {
                float v = (acc[m][n][i] + bv_) * alpha;
                O[(size_t)(row + i) * N + col] = f2bf(v);
            }
        }
}

// ---------------------------------------------------------------------------
// Output GEMM
// ---------------------------------------------------------------------------
__global__ __launch_bounds__(256) void out_gemm(
    const u16* __restrict__ A, const float* __restrict__ W,
    const float* __restrict__ bias, float* __restrict__ O)
{
    constexpr int K = 512, N = 512;
    __shared__ u16 lA[128 * 64];
    __shared__ u16 lB[128 * 64];

    const int tid = threadIdx.x, lane = tid & 63, w = tid >> 6;
    const int wr = w >> 1, wc = w & 1;
    const int bm = blockIdx.x, bn = blockIdx.y;
    const int r0 = tid >> 3, cc = tid & 7;

    f32x4 acc[4][4];
    for (int m = 0; m < 4; ++m)
        for (int n = 0; n < 4; ++n)
            acc[m][n] = f32x4{0.f, 0.f, 0.f, 0.f};

    for (int kt = 0; kt < K; kt += 64) {
        __syncthreads();
        for (int p = 0; p < 4; ++p) {
            int r = r0 + p * 32;
            *(short8*)&lA[r * 64 + ((cc ^ (r & 7)) << 3)] =
                *(const short8*)(A + (size_t)(bm * 128 + r) * K + kt + cc * 8);
            const float4* g = (const float4*)(W + (size_t)(bn * 128 + r) * K + kt + cc * 8);
            float4 f0 = g[0], f1 = g[1];
            short8 v;
            v[0] = (short)f2bf(f0.x); v[1] = (short)f2bf(f0.y);
            v[2] = (short)f2bf(f0.z); v[3] = (short)f2bf(f0.w);
            v[4] = (short)f2bf(f1.x); v[5] = (short)f2bf(f1.y);
            v[6] = (short)f2bf(f1.z); v[7] = (short)f2bf(f1.w);
            *(short8*)&lB[r * 64 + ((cc ^ (r & 7)) << 3)] = v;
        }
        __syncthreads();
        for (int kk = 0; kk < 2; ++kk) {
            bf16x8 af[4], bfr[4];
            for (int m = 0; m < 4; ++m) {
                int row = wr * 64 + m * 16 + (lane & 15);
                af[m] = *(const bf16x8*)&lA[row * 64 + (((kk * 4 + (lane >> 4)) ^ (row & 7)) << 3)];
            }
            for (int n = 0; n < 4; ++n) {
                int row = wc * 64 + n * 16 + (lane & 15);
                bfr[n] = *(const bf16x8*)&lB[row * 64 + (((kk * 4 + (lane >> 4)) ^ (row & 7)) << 3)];
            }
            for (int m = 0; m < 4; ++m)
                for (int n = 0; n < 4; ++n)
                    acc[m][n] = MFMA_BF16(af[m], bfr[n], acc[m][n]);
        }
    }
    for (int m = 0; m < 4; ++m)
        for (int n = 0; n < 4; ++n) {
            int row = bm * 128 + wr * 64 + m * 16 + ((lane >> 4) << 2);
            int col = bn * 128 + wc * 64 + n * 16 + (lane & 15);
            float bv_ = bias[col];
            for (int i = 0; i < 4; ++i)
                O[(size_t)(row + i) * N + col] = acc[m][n][i] + bv_;
        }
}

// ---------------------------------------------------------------------------
// Flash attention v5: in-block KV-split. 8 waves / 512 threads per block:
// group 0 (waves 0-3) does KV[0,1024), group 1 (waves 4-7) KV[1024,2048)
// over the same 64 q-rows; exact flash-merge through LDS at the end.
// 2 blocks/CU x 8 waves = 4 waves/SIMD (2x round-5 occupancy).
// Per group: single-buffered tile pair staged in place, reg-prefetch (T14).
// Zero-shuffle PV via k-slot remap; conflict-free V^T scatter; exp2 softmax;
// defer-max with lane-local check.
// ---------------------------------------------------------------------------
__global__ __launch_bounds__(512, 4) void attn_k(
    const u16* __restrict__ Qp, const u16* __restrict__ Kp, const u16* __restrict__ Vp,
    const unsigned char* __restrict__ mask, u16* __restrict__ Ob)
{
    constexpr int C = 512, NK = 2048, KVH = 1024, NP = KVH / 128;   // 8 pairs/group
    __shared__ u16 lK[2][2][64 * 64];   // [group][tile]
    __shared__ u16 lV[2][2][64 * 64];

    const int tid = threadIdx.x, lane = tid & 63, w = tid >> 6;
    const int g = w >> 2, wg = w & 3;
    const int gd = lane >> 4, q15 = lane & 15;
    const int bh = blockIdx.x, qb = blockIdx.y;
    const int b = bh >> 3, h = bh & 7;
    const size_t qrow0 = (size_t)b * 2048 + qb * 64;
    const size_t krow0 = (size_t)b * 2048;
    const int col0 = h * 64;
    const int rs = tid >> 3, cc = tid & 7;   // 512 threads: rs 0..63, one short8/tile

    // Q fragments in registers (B-operand): lane holds Q[q15][kb*32+gd*8 ..+8]
    bf16x8 qf[2];
    {
        const u16* qrow = Qp + (qrow0 + wg * 16 + q15) * C + col0;
        qf[0] = *(const bf16x8*)(qrow + gd * 8);
        qf[1] = *(const bf16x8*)(qrow + 32 + gd * 8);
    }

    float mst = -1e30f, lstp = 0.f;   // running max (row-uniform) / per-lane partial
    f32x4 oacc[4];
    #pragma unroll
    for (int i = 0; i < 4; ++i) oacc[i] = f32x4{0.f, 0.f, 0.f, 0.f};

    // prologue: all 512 threads prefetch pair 0 for BOTH groups into regs
    short8 kreg[2][2], vreg[2][2];
    #pragma unroll
    for (int g2 = 0; g2 < 2; ++g2)
        #pragma unroll
        for (int u = 0; u < 2; ++u) {
            kreg[g2][u] = *(const short8*)(Kp + (krow0 + g2 * KVH + u * 64 + rs) * C + col0 + cc * 8);
            vreg[g2][u] = *(const short8*)(Vp + (krow0 + g2 * KVH + u * 64 + rs) * C + col0 + cc * 8);
        }

    for (int pj = 0; pj < NP; ++pj) {
        // write prefetched pair to LDS (prev compute done: end-of-iter barrier)
        #pragma unroll
        for (int g2 = 0; g2 < 2; ++g2)
            #pragma unroll
            for (int u = 0; u < 2; ++u) {
                *(short8*)&lK[g2][u][rs * 64 + ((cc ^ (rs & 7)) << 3)] = kreg[g2][u];
                #pragma unroll
                for (int j = 0; j < 8; ++j)
                    lV[g2][u][(cc * 8 + j) * 64 + (((rs >> 3) ^ ((j + cc) & 7)) << 3) + (rs & 7)] = (u16)vreg[g2][u][j];
            }
        // issue next-pair loads (HBM latency hides under compute below)
        if (pj + 1 < NP) {
            #pragma unroll
            for (int g2 = 0; g2 < 2; ++g2)
                #pragma unroll
                for (int u = 0; u < 2; ++u) {
                    const size_t row = krow0 + g2 * KVH + (pj + 1) * 128 + u * 64 + rs;
                    kreg[g2][u] = *(const short8*)(Kp + row * C + col0 + cc * 8);
                    vreg[g2][u] = *(const short8*)(Vp + row * C + col0 + cc * 8);
                }
        }
        __syncthreads();

        const int kvb = g * KVH + pj * 128;
        unsigned char mby[2];
        mby[0] = mask[(size_t)b * NK + kvb + lane];
        mby[1] = mask[(size_t)b * NK + kvb + 64 + lane];

        // QK^T for both tiles of this group's pair
        f32x4 s2[2][4];
        #pragma unroll
        for (int u = 0; u < 2; ++u)
            #pragma unroll
            for (int i = 0; i < 4; ++i) s2[u][i] = f32x4{0.f, 0.f, 0.f, 0.f};
        __builtin_amdgcn_s_setprio(1);
        #pragma unroll
        for (int u = 0; u < 2; ++u) {
            const u16* Kc = &lK[g][u][0];
            #pragma unroll
            for (int kb = 0; kb < 2; ++kb)
                #pragma unroll
                for (int t4 = 0; t4 < 4; ++t4) {
                    int krow = t4 * 16 + q15;
                    bf16x8 kf = *(const bf16x8*)&Kc[krow * 64 + (((kb * 4 + gd) ^ (krow & 7)) << 3)];
                    s2[u][t4] = MFMA_BF16(kf, qf[kb], s2[u][t4]);
                }
        }
        __builtin_amdgcn_s_setprio(0);

        #pragma unroll
        for (int u = 0; u < 2; ++u) {
            unsigned long long m64 = __ballot(mby[u] != 0);
            if (m64) {
                #pragma unroll
                for (int t4 = 0; t4 < 4; ++t4)
                    #pragma unroll
                    for (int i = 0; i < 4; ++i) {
                        int k = t4 * 16 + gd * 4 + i;
                        if ((m64 >> k) & 1ull) s2[u][t4][i] = -1e30f;
                    }
            }

            float pmax = s2[u][0][0];
            #pragma unroll
            for (int t4 = 0; t4 < 4; ++t4)
                #pragma unroll
                for (int i = 0; i < 4; ++i) pmax = fmaxf(pmax, s2[u][t4][i]);

            if (!__all(pmax - mst <= 11.0f)) {
                float rm = fmaxf(pmax, __shfl_xor(pmax, 16));
                rm = fmaxf(rm, __shfl_xor(rm, 32));
                float mn = fmaxf(mst, rm);
                float sf = exp2f(mst - mn);
                mst = mn;
                lstp *= sf;
                #pragma unroll
                for (int i = 0; i < 4; ++i) {
                    float sfi = __shfl(sf, (lane & 48) | ((gd << 2) + i));
                    #pragma unroll
                    for (int t2 = 0; t2 < 4; ++t2) oacc[t2][i] *= sfi;
                }
            }

            float p[4][4];
            float rsum = 0.f;
            #pragma unroll
            for (int t4 = 0; t4 < 4; ++t4)
                #pragma unroll
                for (int i = 0; i < 4; ++i) {
                    float e = fast_exp2(s2[u][t4][i] - mst);
                    p[t4][i] = e;
                    rsum += e;
                }
            lstp += rsum;

            const u16* Vc = &lV[g][u][0];
            __builtin_amdgcn_s_setprio(1);
            #pragma unroll
            for (int kb = 0; kb < 2; ++kb) {
                u32x4 pw;
                pw[0] = cvt_pk_bf16(p[2 * kb][0], p[2 * kb][1]);
                pw[1] = cvt_pk_bf16(p[2 * kb][2], p[2 * kb][3]);
                pw[2] = cvt_pk_bf16(p[2 * kb + 1][0], p[2 * kb + 1][1]);
                pw[3] = cvt_pk_bf16(p[2 * kb + 1][2], p[2 * kb + 1][3]);
                bf16x8 pa = __builtin_bit_cast(bf16x8, pw);
                #pragma unroll
                for (int t2 = 0; t2 < 4; ++t2) {
                    int d = t2 * 16 + q15;
                    int swd = (d + (d >> 3)) & 7;
                    int base = d * 64 + 4 * (gd & 1);
                    uint2 v0 = *(const uint2*)&Vc[base + (((4 * kb + 0 + (gd >> 1)) ^ swd) << 3)];
                    uint2 v1 = *(const uint2*)&Vc[base + (((4 * kb + 2 + (gd >> 1)) ^ swd) << 3)];
                    u32x4 vw; vw[0] = v0.x; vw[1] = v0.y; vw[2] = v1.x; vw[3] = v1.y;
                    bf16x8 vf = __builtin_bit_cast(bf16x8, vw);
                    oacc[t2] = MFMA_BF16(pa, vf, oacc[t2]);
                }
            }
            __builtin_amdgcn_s_setprio(0);
        }
        __syncthreads();   // compute done; next iteration overwrites LDS
    }

    // row-reduce partial sums (lanes sharing q15 across gd)
    float lsum = lstp + __shfl_xor(lstp, 16);
    lsum += __shfl_xor(lsum, 32);

    // merge the two groups through LDS (overlay on lK; loop ended with barrier)
    float* mrg = (float*)&lK[0][0][0];   // [wg*64+lane] x 18 floats = 18 KB
    const int mbase = (wg * 64 + lane) * 18;
    if (g == 1) {
        #pragma unroll
        for (int t2 = 0; t2 < 4; ++t2)
            #pragma unroll
            for (int i = 0; i < 4; ++i) mrg[mbase + t2 * 4 + i] = oacc[t2][i];
        mrg[mbase + 16] = mst;
        mrg[mbase + 17] = lsum;
    }
    __syncthreads();
    if (g == 0) {
        float mst1 = mrg[mbase + 16], ls1 = mrg[mbase + 17];
        float m = fmaxf(mst, mst1);
        float a0 = exp2f(mst - m), a1 = exp2f(mst1 - m);
        float lr = lsum * a0 + ls1 * a1;
        #pragma unroll
        for (int i = 0; i < 4; ++i) {
            int srcl = (lane & 48) | ((gd << 2) + i);
            float a0i = __shfl(a0, srcl), a1i = __shfl(a1, srcl), li = __shfl(lr, srcl);
            float inv = 1.f / li;
            int qg = qb * 64 + wg * 16 + gd * 4 + i;
            #pragma unroll
            for (int t2 = 0; t2 < 4; ++t2) {
                float o1 = mrg[mbase + t2 * 4 + i];
                float vfin = (oacc[t2][i] * a0i + o1 * a1i) * inv;
                Ob[((size_t)b * 2048 + qg) * C + col0 + t2 * 16 + q15] = f2bf(vfin);
            }
        }
    }
}

extern "C" void kernel_launch(void* const* d_in, const int* in_sizes, int n_in,
                              void* d_out, int out_size, void* d_ws, size_t ws_size,
                              hipStream_t stream) {
    const float* query = (const float*)d_in[0];
    const float* key   = (const float*)d_in[1];
    const float* value = (const float*)d_in[2];
    const unsigned char* mask = (const unsigned char*)d_in[3];
    const float* Wq = (const float*)d_in[4];
    const float* bq = (const float*)d_in[5];
    const float* Wk = (const float*)d_in[6];
    const float* bk = (const float*)d_in[7];
    const float* Wv = (const float*)d_in[8];
    const float* bv = (const float*)d_in[9];
    const float* Wo = (const float*)d_in[10];
    const float* bo = (const float*)d_in[11];

    u16* ws = (u16*)d_ws;
    u16* Qp = ws;
    u16* Kp = ws + 2097152;
    u16* Vp = ws + 4194304;
    u16* Ob = ws + 6291456;

    dim3 gp(32, 4, 3);
    proj_gemm<<<gp, 256, 0, stream>>>(query, key, value, Wq, Wk, Wv, bq, bk, bv, Qp, Kp, Vp);

    dim3 ga(16, 32);   // x = bh (XCD locality for K/V), y = q-tile
    attn_k<<<ga, 512, 0, stream>>>(Qp, Kp, Vp, mask, Ob);

    dim3 go(32, 4);
    out_gemm<<<go, 256, 0, stream>>>(Ob, Wo, bo, (float*)d_out);
}

// Round 7
// 79.308 us; speedup vs baseline: 1.4390x; 1.4390x over previous
//
#include <hip/hip_runtime.h>

typedef unsigned short u16;
typedef __attribute__((ext_vector_type(8))) short short8;
typedef __attribute__((ext_vector_type(8))) __bf16 bf16x8;
typedef __attribute__((ext_vector_type(4))) float f32x4;
typedef __attribute__((ext_vector_type(4))) unsigned int u32x4;

#define MFMA_BF16(a, b, c) __builtin_amdgcn_mfma_f32_16x16x32_bf16((a), (b), (c), 0, 0, 0)

__device__ __forceinline__ u16 f2bf(float f) {
    unsigned u = __builtin_bit_cast(unsigned, f);
    u += 0x7FFFu + ((u >> 16) & 1u);   // round-to-nearest-even; inputs finite
    return (u16)(u >> 16);
}

// v_cvt_pk_bf16_f32: dst = {bf16(lo), bf16(hi)} packed, RNE
__device__ __forceinline__ unsigned cvt_pk_bf16(float lo, float hi) {
    unsigned r;
    asm("v_cvt_pk_bf16_f32 %0, %1, %2" : "=v"(r) : "v"(lo), "v"(hi));
    return r;
}

// raw v_exp_f32 (exp2); denormal range flushes to 0, which is what we want
__device__ __forceinline__ float fast_exp2(float x) {
    float r;
    asm("v_exp_f32 %0, %1" : "=v"(r) : "v"(x));
    return r;
}

// ---------------------------------------------------------------------------
// Projection GEMM: O[n][c] = bf16( (X[n][:] . W[c][:] + b[c]) * alpha )
// alpha_q = SCALE * log2(e) so attention softmax can use exp2 directly.
// ---------------------------------------------------------------------------
__global__ __launch_bounds__(256) void proj_gemm(
    const float* __restrict__ Xq, const float* __restrict__ Xk, const float* __restrict__ Xv,
    const float* __restrict__ Wq, const float* __restrict__ Wk, const float* __restrict__ Wv,
    const float* __restrict__ bq, const float* __restrict__ bk, const float* __restrict__ bv,
    u16* __restrict__ Oq, u16* __restrict__ Ok, u16* __restrict__ Ov)
{
    constexpr int K = 512, N = 512;
    const int z = blockIdx.z;
    const float* __restrict__ X = (z == 0) ? Xq : (z == 1) ? Xk : Xv;
    const float* __restrict__ W = (z == 0) ? Wq : (z == 1) ? Wk : Wv;
    const float* __restrict__ bias = (z == 0) ? bq : (z == 1) ? bk : bv;
    u16* __restrict__ O = (z == 0) ? Oq : (z == 1) ? Ok : Ov;
    const float alpha = (z == 0) ? 0.125f * 1.44269504088896f : 1.0f;

    __shared__ u16 lA[128 * 64];
    __shared__ u16 lB[128 * 64];

    const int tid = threadIdx.x, lane = tid & 63, w = tid >> 6;
    const int wr = w >> 1, wc = w & 1;
    const int bm = blockIdx.x, bn = blockIdx.y;
    const int r0 = tid >> 3, cc = tid & 7;

    f32x4 acc[4][4];
    for (int m = 0; m < 4; ++m)
        for (int n = 0; n < 4; ++n)
            acc[m][n] = f32x4{0.f, 0.f, 0.f, 0.f};

    for (int kt = 0; kt < K; kt += 64) {
        __syncthreads();
        for (int p = 0; p < 4; ++p) {
            int r = r0 + p * 32;
            {
                const float4* g = (const float4*)(X + (size_t)(bm * 128 + r) * K + kt + cc * 8);
                float4 f0 = g[0], f1 = g[1];
                short8 v;
                v[0] = (short)f2bf(f0.x); v[1] = (short)f2bf(f0.y);
                v[2] = (short)f2bf(f0.z); v[3] = (short)f2bf(f0.w);
                v[4] = (short)f2bf(f1.x); v[5] = (short)f2bf(f1.y);
                v[6] = (short)f2bf(f1.z); v[7] = (short)f2bf(f1.w);
                *(short8*)&lA[r * 64 + ((cc ^ (r & 7)) << 3)] = v;
            }
            {
                const float4* g = (const float4*)(W + (size_t)(bn * 128 + r) * K + kt + cc * 8);
                float4 f0 = g[0], f1 = g[1];
                short8 v;
                v[0] = (short)f2bf(f0.x); v[1] = (short)f2bf(f0.y);
                v[2] = (short)f2bf(f0.z); v[3] = (short)f2bf(f0.w);
                v[4] = (short)f2bf(f1.x); v[5] = (short)f2bf(f1.y);
                v[6] = (short)f2bf(f1.z); v[7] = (short)f2bf(f1.w);
                *(short8*)&lB[r * 64 + ((cc ^ (r & 7)) << 3)] = v;
            }
        }
        __syncthreads();
        for (int kk = 0; kk < 2; ++kk) {
            bf16x8 af[4], bfr[4];
            for (int m = 0; m < 4; ++m) {
                int row = wr * 64 + m * 16 + (lane & 15);
                af[m] = *(const bf16x8*)&lA[row * 64 + (((kk * 4 + (lane >> 4)) ^ (row & 7)) << 3)];
            }
            for (int n = 0; n < 4; ++n) {
                int row = wc * 64 + n * 16 + (lane & 15);
                bfr[n] = *(const bf16x8*)&lB[row * 64 + (((kk * 4 + (lane >> 4)) ^ (row & 7)) << 3)];
            }
            for (int m = 0; m < 4; ++m)
                for (int n = 0; n < 4; ++n)
                    acc[m][n] = MFMA_BF16(af[m], bfr[n], acc[m][n]);
        }
    }
    for (int m = 0; m < 4; ++m)
        for (int n = 0; n < 4; ++n) {
            int row = bm * 128 + wr * 64 + m * 16 + ((lane >> 4) << 2);
            int col = bn * 128 + wc * 64 + n * 16 + (lane & 15);
            float bv_ = bias[col];
            for (int i = 0; i < 4; ++i) {
                float v = (acc[m][n][i] + bv_) * alpha;
                O[(size_t)(row + i) * N + col] = f2bf(v);
            }
        }
}

// ---------------------------------------------------------------------------
// Output GEMM
// ---------------------------------------------------------------------------
__global__ __launch_bounds__(256) void out_gemm(
    const u16* __restrict__ A, const float* __restrict__ W,
    const float* __restrict__ bias, float* __restrict__ O)
{
    constexpr int K = 512, N = 512;
    __shared__ u16 lA[128 * 64];
    __shared__ u16 lB[128 * 64];

    const int tid = threadIdx.x, lane = tid & 63, w = tid >> 6;
    const int wr = w >> 1, wc = w & 1;
    const int bm = blockIdx.x, bn = blockIdx.y;
    const int r0 = tid >> 3, cc = tid & 7;

    f32x4 acc[4][4];
    for (int m = 0; m < 4; ++m)
        for (int n = 0; n < 4; ++n)
            acc[m][n] = f32x4{0.f, 0.f, 0.f, 0.f};

    for (int kt = 0; kt < K; kt += 64) {
        __syncthreads();
        for (int p = 0; p < 4; ++p) {
            int r = r0 + p * 32;
            *(short8*)&lA[r * 64 + ((cc ^ (r & 7)) << 3)] =
                *(const short8*)(A + (size_t)(bm * 128 + r) * K + kt + cc * 8);
            const float4* g = (const float4*)(W + (size_t)(bn * 128 + r) * K + kt + cc * 8);
            float4 f0 = g[0], f1 = g[1];
            short8 v;
            v[0] = (short)f2bf(f0.x); v[1] = (short)f2bf(f0.y);
            v[2] = (short)f2bf(f0.z); v[3] = (short)f2bf(f0.w);
            v[4] = (short)f2bf(f1.x); v[5] = (short)f2bf(f1.y);
            v[6] = (short)f2bf(f1.z); v[7] = (short)f2bf(f1.w);
            *(short8*)&lB[r * 64 + ((cc ^ (r & 7)) << 3)] = v;
        }
        __syncthreads();
        for (int kk = 0; kk < 2; ++kk) {
            bf16x8 af[4], bfr[4];
            for (int m = 0; m < 4; ++m) {
                int row = wr * 64 + m * 16 + (lane & 15);
                af[m] = *(const bf16x8*)&lA[row * 64 + (((kk * 4 + (lane >> 4)) ^ (row & 7)) << 3)];
            }
            for (int n = 0; n < 4; ++n) {
                int row = wc * 64 + n * 16 + (lane & 15);
                bfr[n] = *(const bf16x8*)&lB[row * 64 + (((kk * 4 + (lane >> 4)) ^ (row & 7)) << 3)];
            }
            for (int m = 0; m < 4; ++m)
                for (int n = 0; n < 4; ++n)
                    acc[m][n] = MFMA_BF16(af[m], bfr[n], acc[m][n]);
        }
    }
    for (int m = 0; m < 4; ++m)
        for (int n = 0; n < 4; ++n) {
            int row = bm * 128 + wr * 64 + m * 16 + ((lane >> 4) << 2);
            int col = bn * 128 + wc * 64 + n * 16 + (lane & 15);
            float bv_ = bias[col];
            for (int i = 0; i < 4; ++i)
                O[(size_t)(row + i) * N + col] = acc[m][n][i] + bv_;
        }
}

// ---------------------------------------------------------------------------
// Flash attention v5b: in-block KV-split, 8 waves / 512 threads per block.
// Same as round-6 EXCEPT __launch_bounds__(512, 2): empirically on B=512 this
// toolchain caps VGPR at 512/(arg*2); arg=4 forced 64 VGPR -> massive scratch
// spills (WRITE_SIZE 169 MB). arg=2 -> cap 128 (kernel needs ~124), giving
// 2 blocks/CU x 8 waves = 4 waves/SIMD with no spill.
// ---------------------------------------------------------------------------
__global__ __launch_bounds__(512, 2) void attn_k(
    const u16* __restrict__ Qp, const u16* __restrict__ Kp, const u16* __restrict__ Vp,
    const unsigned char* __restrict__ mask, u16* __restrict__ Ob)
{
    constexpr int C = 512, NK = 2048, KVH = 1024, NP = KVH / 128;   // 8 pairs/group
    __shared__ u16 lK[2][2][64 * 64];   // [group][tile]
    __shared__ u16 lV[2][2][64 * 64];

    const int tid = threadIdx.x, lane = tid & 63, w = tid >> 6;
    const int g = w >> 2, wg = w & 3;
    const int gd = lane >> 4, q15 = lane & 15;
    const int bh = blockIdx.x, qb = blockIdx.y;
    const int b = bh >> 3, h = bh & 7;
    const size_t qrow0 = (size_t)b * 2048 + qb * 64;
    const size_t krow0 = (size_t)b * 2048;
    const int col0 = h * 64;
    const int rs = tid >> 3, cc = tid & 7;   // 512 threads: rs 0..63, one short8/tile

    // Q fragments in registers (B-operand): lane holds Q[q15][kb*32+gd*8 ..+8]
    bf16x8 qf[2];
    {
        const u16* qrow = Qp + (qrow0 + wg * 16 + q15) * C + col0;
        qf[0] = *(const bf16x8*)(qrow + gd * 8);
        qf[1] = *(const bf16x8*)(qrow + 32 + gd * 8);
    }

    float mst = -1e30f, lstp = 0.f;   // running max (row-uniform) / per-lane partial
    f32x4 oacc[4];
    #pragma unroll
    for (int i = 0; i < 4; ++i) oacc[i] = f32x4{0.f, 0.f, 0.f, 0.f};

    // prologue: all 512 threads prefetch pair 0 for BOTH groups into regs
    short8 kreg[2][2], vreg[2][2];
    #pragma unroll
    for (int g2 = 0; g2 < 2; ++g2)
        #pragma unroll
        for (int u = 0; u < 2; ++u) {
            kreg[g2][u] = *(const short8*)(Kp + (krow0 + g2 * KVH + u * 64 + rs) * C + col0 + cc * 8);
            vreg[g2][u] = *(const short8*)(Vp + (krow0 + g2 * KVH + u * 64 + rs) * C + col0 + cc * 8);
        }

    for (int pj = 0; pj < NP; ++pj) {
        // write prefetched pair to LDS (prev compute done: end-of-iter barrier)
        #pragma unroll
        for (int g2 = 0; g2 < 2; ++g2)
            #pragma unroll
            for (int u = 0; u < 2; ++u) {
                *(short8*)&lK[g2][u][rs * 64 + ((cc ^ (rs & 7)) << 3)] = kreg[g2][u];
                #pragma unroll
                for (int j = 0; j < 8; ++j)
                    lV[g2][u][(cc * 8 + j) * 64 + (((rs >> 3) ^ ((j + cc) & 7)) << 3) + (rs & 7)] = (u16)vreg[g2][u][j];
            }
        // issue next-pair loads (HBM latency hides under compute below)
        if (pj + 1 < NP) {
            #pragma unroll
            for (int g2 = 0; g2 < 2; ++g2)
                #pragma unroll
                for (int u = 0; u < 2; ++u) {
                    const size_t row = krow0 + g2 * KVH + (pj + 1) * 128 + u * 64 + rs;
                    kreg[g2][u] = *(const short8*)(Kp + row * C + col0 + cc * 8);
                    vreg[g2][u] = *(const short8*)(Vp + row * C + col0 + cc * 8);
                }
        }
        __syncthreads();

        const int kvb = g * KVH + pj * 128;
        unsigned char mby[2];
        mby[0] = mask[(size_t)b * NK + kvb + lane];
        mby[1] = mask[(size_t)b * NK + kvb + 64 + lane];

        // QK^T for both tiles of this group's pair
        f32x4 s2[2][4];
        #pragma unroll
        for (int u = 0; u < 2; ++u)
            #pragma unroll
            for (int i = 0; i < 4; ++i) s2[u][i] = f32x4{0.f, 0.f, 0.f, 0.f};
        __builtin_amdgcn_s_setprio(1);
        #pragma unroll
        for (int u = 0; u < 2; ++u) {
            const u16* Kc = &lK[g][u][0];
            #pragma unroll
            for (int kb = 0; kb < 2; ++kb)
                #pragma unroll
                for (int t4 = 0; t4 < 4; ++t4) {
                    int krow = t4 * 16 + q15;
                    bf16x8 kf = *(const bf16x8*)&Kc[krow * 64 + (((kb * 4 + gd) ^ (krow & 7)) << 3)];
                    s2[u][t4] = MFMA_BF16(kf, qf[kb], s2[u][t4]);
                }
        }
        __builtin_amdgcn_s_setprio(0);

        #pragma unroll
        for (int u = 0; u < 2; ++u) {
            unsigned long long m64 = __ballot(mby[u] != 0);
            if (m64) {
                #pragma unroll
                for (int t4 = 0; t4 < 4; ++t4)
                    #pragma unroll
                    for (int i = 0; i < 4; ++i) {
                        int k = t4 * 16 + gd * 4 + i;
                        if ((m64 >> k) & 1ull) s2[u][t4][i] = -1e30f;
                    }
            }

            float pmax = s2[u][0][0];
            #pragma unroll
            for (int t4 = 0; t4 < 4; ++t4)
                #pragma unroll
                for (int i = 0; i < 4; ++i) pmax = fmaxf(pmax, s2[u][t4][i]);

            if (!__all(pmax - mst <= 11.0f)) {
                float rm = fmaxf(pmax, __shfl_xor(pmax, 16));
                rm = fmaxf(rm, __shfl_xor(rm, 32));
                float mn = fmaxf(mst, rm);
                float sf = exp2f(mst - mn);
                mst = mn;
                lstp *= sf;
                #pragma unroll
                for (int i = 0; i < 4; ++i) {
                    float sfi = __shfl(sf, (lane & 48) | ((gd << 2) + i));
                    #pragma unroll
                    for (int t2 = 0; t2 < 4; ++t2) oacc[t2][i] *= sfi;
                }
            }

            float p[4][4];
            float rsum = 0.f;
            #pragma unroll
            for (int t4 = 0; t4 < 4; ++t4)
                #pragma unroll
                for (int i = 0; i < 4; ++i) {
                    float e = fast_exp2(s2[u][t4][i] - mst);
                    p[t4][i] = e;
                    rsum += e;
                }
            lstp += rsum;

            const u16* Vc = &lV[g][u][0];
            __builtin_amdgcn_s_setprio(1);
            #pragma unroll
            for (int kb = 0; kb < 2; ++kb) {
                u32x4 pw;
                pw[0] = cvt_pk_bf16(p[2 * kb][0], p[2 * kb][1]);
                pw[1] = cvt_pk_bf16(p[2 * kb][2], p[2 * kb][3]);
                pw[2] = cvt_pk_bf16(p[2 * kb + 1][0], p[2 * kb + 1][1]);
                pw[3] = cvt_pk_bf16(p[2 * kb + 1][2], p[2 * kb + 1][3]);
                bf16x8 pa = __builtin_bit_cast(bf16x8, pw);
                #pragma unroll
                for (int t2 = 0; t2 < 4; ++t2) {
                    int d = t2 * 16 + q15;
                    int swd = (d + (d >> 3)) & 7;
                    int base = d * 64 + 4 * (gd & 1);
                    uint2 v0 = *(const uint2*)&Vc[base + (((4 * kb + 0 + (gd >> 1)) ^ swd) << 3)];
                    uint2 v1 = *(const uint2*)&Vc[base + (((4 * kb + 2 + (gd >> 1)) ^ swd) << 3)];
                    u32x4 vw; vw[0] = v0.x; vw[1] = v0.y; vw[2] = v1.x; vw[3] = v1.y;
                    bf16x8 vf = __builtin_bit_cast(bf16x8, vw);
                    oacc[t2] = MFMA_BF16(pa, vf, oacc[t2]);
                }
            }
            __builtin_amdgcn_s_setprio(0);
        }
        __syncthreads();   // compute done; next iteration overwrites LDS
    }

    // row-reduce partial sums (lanes sharing q15 across gd)
    float lsum = lstp + __shfl_xor(lstp, 16);
    lsum += __shfl_xor(lsum, 32);

    // merge the two groups through LDS (overlay on lK; loop ended with barrier)
    float* mrg = (float*)&lK[0][0][0];   // 256 rows x 18 floats = 18 KB (< 32 KB lK)
    const int mbase = (wg * 64 + lane) * 18;
    if (g == 1) {
        #pragma unroll
        for (int t2 = 0; t2 < 4; ++t2)
            #pragma unroll
            for (int i = 0; i < 4; ++i) mrg[mbase + t2 * 4 + i] = oacc[t2][i];
        mrg[mbase + 16] = mst;
        mrg[mbase + 17] = lsum;
    }
    __syncthreads();
    if (g == 0) {
        float mst1 = mrg[mbase + 16], ls1 = mrg[mbase + 17];
        float m = fmaxf(mst, mst1);
        float a0 = exp2f(mst - m), a1 = exp2f(mst1 - m);
        float lr = lsum * a0 + ls1 * a1;
        #pragma unroll
        for (int i = 0; i < 4; ++i) {
            int srcl = (lane & 48) | ((gd << 2) + i);
            float a0i = __shfl(a0, srcl), a1i = __shfl(a1, srcl), li = __shfl(lr, srcl);
            float inv = 1.f / li;
            int qg = qb * 64 + wg * 16 + gd * 4 + i;
            #pragma unroll
            for (int t2 = 0; t2 < 4; ++t2) {
                float o1 = mrg[mbase + t2 * 4 + i];
                float vfin = (oacc[t2][i] * a0i + o1 * a1i) * inv;
                Ob[((size_t)b * 2048 + qg) * C + col0 + t2 * 16 + q15] = f2bf(vfin);
            }
        }
    }
}

extern "C" void kernel_launch(void* const* d_in, const int* in_sizes, int n_in,
                              void* d_out, int out_size, void* d_ws, size_t ws_size,
                              hipStream_t stream) {
    const float* query = (const float*)d_in[0];
    const float* key   = (const float*)d_in[1];
    const float* value = (const float*)d_in[2];
    const unsigned char* mask = (const unsigned char*)d_in[3];
    const float* Wq = (const float*)d_in[4];
    const float* bq = (const float*)d_in[5];
    const float* Wk = (const float*)d_in[6];
    const float* bk = (const float*)d_in[7];
    const float* Wv = (const float*)d_in[8];
    const float* bv = (const float*)d_in[9];
    const float* Wo = (const float*)d_in[10];
    const float* bo = (const float*)d_in[11];

    u16* ws = (u16*)d_ws;
    u16* Qp = ws;
    u16* Kp = ws + 2097152;
    u16* Vp = ws + 4194304;
    u16* Ob = ws + 6291456;

    dim3 gp(32, 4, 3);
    proj_gemm<<<gp, 256, 0, stream>>>(query, key, value, Wq, Wk, Wv, bq, bk, bv, Qp, Kp, Vp);

    dim3 ga(16, 32);   // x = bh (XCD locality for K/V), y = q-tile
    attn_k<<<ga, 512, 0, stream>>>(Qp, Kp, Vp, mask, Ob);

    dim3 go(32, 4);
    out_gemm<<<go, 256, 0, stream>>>(Ob, Wo, bo, (float*)d_out);
}